// Round 1
// 126.952 us; speedup vs baseline: 1.0202x; 1.0202x over previous
//
#include <hip/hip_runtime.h>
#include <stdint.h>
#include <float.h>

using u64 = unsigned long long;
typedef float v2f __attribute__((ext_vector_type(2)));

constexpr int B_ = 2;
constexpr int NC = 512;
constexpr int NF = 8192;
constexpr int MT = 8192;

constexpr int TPB  = 256;
constexpr int RPB  = 512;          // rows per block (2 per thread, packed as v2f)
constexpr int TILE = 256;
constexpr int CF   = 16;           // fine chunks (j-split) -> 512 j per chunk
constexpr int TAIL_BLOCKS = 196;   // 64 fine-rows + 64 fine-cols + 4 coarse-rows + 64 coarse-cols

#define DEVINL __device__ __forceinline__

// ---------------------------------------------------------------------------
// pairmin: each block computes, for RPB rows of P, the min over its j-chunk of
//   d = max((xx+qq) - 2*xy, 0)
// computed bit-exactly vs numpy fp32:
//   2*xy is computed as ((2x0)q0 + (2x1)q1) + (2x2)q2  — power-of-2 scaling
//   commutes with round-to-nearest, so this equals 2*((x0q0+x1q1)+x2q2) exactly.
// The max(.,0) clamp is applied ONCE at pack time: clamp is monotone, so
//   max(min_j d_j, 0) == min_j max(d_j, 0)   (bit-exact for the value).
// The argmin index can only differ from the clamped-per-j ordering if one row
// has >= 2 computed-NEGATIVE distances (two targets within ~1e-3 of the same
// fine point) — measure-zero for this data.
// Inner loop: 8-deep ping-pong register prefetch from LDS, 16 j per iteration,
// v2f packing (2 rows) so the compiler emits v_pk_*_f32.
// Results go to per-chunk partial slots: NO atomics, NO sentinel init.
// ---------------------------------------------------------------------------
template<bool ARGMIN>
DEVINL void pairmin_body(const float* __restrict__ P, const float* __restrict__ Q,
                         int nP, int nQ, int b, int row_base, int j0, int ntiles,
                         int chunk, int nRowsTot,
                         u64* __restrict__ outPack, unsigned* __restrict__ outVal,
                         float4* tile)
{
#pragma clang fp contract(off)
    const int tid  = threadIdx.x;
    const int row0 = row_base + tid;
    const int row1 = row_base + tid + TPB;
    const float* p0 = P + ((size_t)b * nP + row0) * 3;
    const float* p1 = P + ((size_t)b * nP + row1) * 3;
    float a0 = p0[0], a1 = p0[1], a2 = p0[2];
    float e0 = p1[0], e1 = p1[1], e2 = p1[2];
    v2f tx0 = {2.0f * a0, 2.0f * e0};
    v2f tx1 = {2.0f * a1, 2.0f * e1};
    v2f tx2 = {2.0f * a2, 2.0f * e2};
    v2f txx = {(a0*a0 + a1*a1) + a2*a2, (e0*e0 + e1*e1) + e2*e2};
    v2f dbest = {FLT_MAX, FLT_MAX};
    int jb0 = 0, jb1 = 0;

    // distance eval: 5 pk (dot, contract off) + pk_add + pk_sub, then min/idx
    auto PROC = [&](const float4 qv, const int j) {
#pragma clang fp contract(off)
        v2f s = (tx0 * qv.x + tx1 * qv.y) + tx2 * qv.z;   // == 2*xy, exact
        v2f d = (txx + qv.w) - s;                          // (xx+qq) - 2xy
        if (ARGMIN) {
            bool c0 = d.x < dbest.x;                       // strict: first idx wins
            bool c1 = d.y < dbest.y;
            dbest = __builtin_elementwise_min(d, dbest);
            jb0 = c0 ? j : jb0;
            jb1 = c1 ? j : jb1;
        } else {
            dbest = __builtin_elementwise_min(dbest, d);
        }
    };

    // stage-ahead registers for tile t (hides global latency under compute)
    {
        const float* q = Q + ((size_t)b * nQ + j0 + tid) * 3;
        float nq0 = q[0], nq1 = q[1], nq2 = q[2];

        for (int t = 0; t < ntiles; ++t) {
            __syncthreads();
            tile[tid] = make_float4(nq0, nq1, nq2, (nq0*nq0 + nq1*nq1) + nq2*nq2);
            if (t + 1 < ntiles) {
                const float* qn = Q + ((size_t)b * nQ + j0 + (t + 1) * TILE + tid) * 3;
                nq0 = qn[0]; nq1 = qn[1]; nq2 = qn[2];
            }
            __syncthreads();
            const int jbase = j0 + t * TILE;

            float4 qa[8], qb[8];
            #pragma unroll
            for (int u = 0; u < 8; ++u) qa[u] = tile[u];

            for (int jj = 0; jj < TILE; jj += 16) {
                #pragma unroll
                for (int u = 0; u < 8; ++u) qb[u] = tile[jj + 8 + u];
                #pragma unroll
                for (int u = 0; u < 8; ++u) PROC(qa[u], jbase + jj + u);
                #pragma unroll
                for (int u = 0; u < 8; ++u) qa[u] = tile[(jj + 16 + u) & (TILE - 1)];
                #pragma unroll
                for (int u = 0; u < 8; ++u) PROC(qb[u], jbase + jj + 8 + u);
            }
        }
    }

    const v2f vzero = {0.0f, 0.0f};
    v2f dcl = __builtin_elementwise_max(dbest, vzero);     // clamp once, exact
    const size_t o0 = (size_t)chunk * nRowsTot + (size_t)b * nP;
    if (ARGMIN) {
        outPack[o0 + row0] = ((u64)__float_as_uint(dcl.x) << 32) | (unsigned)jb0;
        outPack[o0 + row1] = ((u64)__float_as_uint(dcl.y) << 32) | (unsigned)jb1;
    } else {
        outVal[o0 + row0] = __float_as_uint(dcl.x);
        outVal[o0 + row1] = __float_as_uint(dcl.y);
    }
}

// All four pairwise passes, one dispatch, 1152 blocks.
//  [0,   64)  coarse-rows : P=coarse(512), Q=tgt,    32 chunks x 2b, 1 tile
//  [64, 128)  coarse-cols : P=tgt(8192),  Q=coarse,  2 chunks x 16yb x 2b, 1 tile
//  [128, 640) fine-rows   : P=fine(8192), Q=tgt,  ARGMIN, 16 chunks x 16yb x 2b, 2 tiles
//  [640,1152) fine-cols   : P=tgt(8192),  Q=fine,         16 chunks x 16yb x 2b, 2 tiles
// launch_bounds (256,4): allow up to ~128 VGPR so the 8-deep prefetch stays in
// registers; ILP replaces the occupancy we weren't getting anyway (30%).
__global__ __launch_bounds__(TPB, 4) void pairmin_all(
    const float* __restrict__ coarse, const float* __restrict__ fine,
    const float* __restrict__ tgt,
    u64* __restrict__ pfr, unsigned* __restrict__ pfc,
    unsigned* __restrict__ pcr, unsigned* __restrict__ pcc,
    unsigned* __restrict__ counter)
{
    __shared__ float4 tile[TILE];
    const int bx = blockIdx.x;
    if (bx == 0 && threadIdx.x == 0) *counter = 0;   // init for tail_all
    if (bx < 64) {
        int chunk = bx & 31, b = bx >> 5;
        pairmin_body<false>(coarse, tgt, NC, MT, b, 0, chunk * TILE, 1,
                            chunk, B_ * NC, nullptr, pcr, tile);
    } else if (bx < 128) {
        int i = bx - 64;
        int chunk = i & 1, yb = (i >> 1) & 15, b = i >> 5;
        pairmin_body<false>(tgt, coarse, MT, NC, b, yb * RPB, chunk * TILE, 1,
                            chunk, B_ * MT, nullptr, pcc, tile);
    } else if (bx < 640) {
        int i = bx - 128;
        int chunk = i & 15, yb = (i >> 4) & 15, b = i >> 8;
        pairmin_body<true>(fine, tgt, NF, MT, b, yb * RPB, chunk * (MT / CF), 2,
                           chunk, B_ * NF, pfr, nullptr, tile);
    } else {
        int i = bx - 640;
        int chunk = i & 15, yb = (i >> 4) & 15, b = i >> 8;
        pairmin_body<false>(tgt, fine, MT, NF, b, yb * RPB, chunk * (NF / CF), 2,
                            chunk, B_ * MT, nullptr, pfc, tile);
    }
}

// ---------------------------------------------------------------------------
// tail_all: everything after the pairwise passes, one dispatch.
//  [0,  64) fine-rows: reduce 16 partials (u64 min = min d then min j), gather,
//           chamfer d1 sum, loss_ref/rot stats, wedge volumes (LDS halo).
//  [64,128) fine-cols value reduce -> d2f
//  [128,132) coarse-rows -> d1c
//  [132,196) coarse-cols -> d2c
// Each block writes its partial sums to bs[bx][16]; last-arriving block (via
// device-scope counter) reduces bs and writes the final scalar.
// ---------------------------------------------------------------------------
__global__ __launch_bounds__(TPB) void tail_all(
    const float* __restrict__ fine, const float* __restrict__ tgt,
    const u64* __restrict__ pfr, const unsigned* __restrict__ pfc,
    const unsigned* __restrict__ pcr, const unsigned* __restrict__ pcc,
    double* __restrict__ bs, unsigned* __restrict__ counter,
    float* __restrict__ out)
{
    __shared__ float sp[TPB + 2][3], yp[TPB + 2][3];
    __shared__ double redw[4][9];
    __shared__ double lred[4][13];
    __shared__ int lastflag;
    const int bx = blockIdx.x, tid = threadIdx.x;
    const int wave = tid >> 6, lane = tid & 63;

    double v_s = 0, v_d2f = 0, v_d1c = 0, v_d2c = 0, v_yd2 = 0, v_zs = 0, v_zt = 0;
    double vs = 0, vt = 0;
    int role_b = 0;

    if (bx < 64) {                              // ---- fine-rows ----
        const int base = bx * TPB;
        const int g = base + tid;
        const int b = base >> 13;  role_b = b;
        u64 best = pfr[g];
        #pragma unroll
        for (int c = 1; c < CF; ++c) {
            u64 p = pfr[(size_t)c * (B_ * NF) + g];
            best = p < best ? p : best;
        }
        float d1 = __uint_as_float((unsigned)(best >> 32));
        int idx  = (int)(best & 0xffffffffULL);
        float s = sqrtf(fmaxf(d1, 1e-12f));
        const float* y  = tgt  + ((size_t)b * MT + idx) * 3;
        const float* sr = fine + (size_t)g * 3;
        float y0 = y[0],  y1 = y[1],  y2 = y[2];
        float s0 = sr[0], s1 = sr[1], s2 = sr[2];
        yp[tid][0] = y0; yp[tid][1] = y1; yp[tid][2] = y2;
        sp[tid][0] = s0; sp[tid][1] = s1; sp[tid][2] = s2;
        const int base_b = base & (NF - 1);
        if (tid < 2 && base_b + TPB + tid < NF) {        // halo rows
            int g2 = base + TPB + tid;
            u64 b2 = pfr[g2];
            #pragma unroll
            for (int c = 1; c < CF; ++c) {
                u64 p = pfr[(size_t)c * (B_ * NF) + g2];
                b2 = p < b2 ? p : b2;
            }
            int i2 = (int)(b2 & 0xffffffffULL);
            const float* yh = tgt  + ((size_t)b * MT + i2) * 3;
            const float* sh = fine + (size_t)g2 * 3;
            #pragma unroll
            for (int k = 0; k < 3; ++k) { yp[TPB + tid][k] = yh[k]; sp[TPB + tid][k] = sh[k]; }
        }
        __syncthreads();
        v_s = s;
        float yd = s1 - y1;
        v_yd2 = (double)(yd * yd);
        v_zs  = (double)(s2 * s2);
        v_zt  = (double)(y2 * y2);
        int rb = base_b + tid;
        if (rb <= NF - 3) {          // same f32 exprs as the verified R3 kernel
            {
                const float* a = sp[tid]; const float* c = sp[tid+1]; const float* e = sp[tid+2];
                float c0 = a[1]*c[2] - a[2]*c[1];
                float c1 = a[2]*c[0] - a[0]*c[2];
                float c2 = a[0]*c[1] - a[1]*c[0];
                vs = (double)(c0*e[0] + c1*e[1] + c2*e[2]);
            }
            {
                const float* a = yp[tid]; const float* c = yp[tid+1]; const float* e = yp[tid+2];
                float c0 = a[1]*c[2] - a[2]*c[1];
                float c1 = a[2]*c[0] - a[0]*c[2];
                float c2 = a[0]*c[1] - a[1]*c[0];
                vt = (double)(c0*e[0] + c1*e[1] + c2*e[2]);
            }
        }
    } else if (bx < 128) {                      // ---- fine-cols ----
        const int g = (bx - 64) * TPB + tid;
        unsigned best = pfc[g];
        #pragma unroll
        for (int c = 1; c < CF; ++c) best = min(best, pfc[(size_t)c * (B_ * MT) + g]);
        v_d2f = (double)sqrtf(fmaxf(__uint_as_float(best), 1e-12f));
    } else if (bx < 132) {                      // ---- coarse-rows ----
        const int g = (bx - 128) * TPB + tid;
        unsigned best = pcr[g];
        #pragma unroll
        for (int c = 1; c < 32; ++c) best = min(best, pcr[(size_t)c * (B_ * NC) + g]);
        v_d1c = (double)sqrtf(fmaxf(__uint_as_float(best), 1e-12f));
    } else {                                    // ---- coarse-cols ----
        const int g = (bx - 132) * TPB + tid;
        unsigned best = min(pcc[g], pcc[(size_t)(B_ * MT) + g]);
        v_d2c = (double)sqrtf(fmaxf(__uint_as_float(best), 1e-12f));
    }

    // block reduce 9 values
    double r9[9] = {v_s, v_d2f, v_d1c, v_d2c, v_yd2, v_zs, v_zt, vs, vt};
    for (int o = 32; o; o >>= 1) {
        #pragma unroll
        for (int k = 0; k < 9; ++k) r9[k] += __shfl_down(r9[k], o);
    }
    if (lane == 0) {
        #pragma unroll
        for (int k = 0; k < 9; ++k) redw[wave][k] = r9[k];
    }
    __syncthreads();
    if (tid == 0) {
        double t9[9];
        #pragma unroll
        for (int k = 0; k < 9; ++k)
            t9[k] = redw[0][k] + redw[1][k] + redw[2][k] + redw[3][k];
        double* o = bs + (size_t)bx * 16;
        #pragma unroll
        for (int k = 0; k < 16; ++k) o[k] = 0.0;
        o[0] = t9[0]; o[1] = t9[1]; o[2] = t9[2]; o[3] = t9[3]; o[4] = t9[4];
        o[5 + role_b]  = t9[5];   // zs
        o[7 + role_b]  = t9[6];   // zt
        o[9 + role_b]  = t9[7];   // vs
        o[11 + role_b] = t9[8];   // vt
        __threadfence();
        unsigned old = atomicAdd(counter, 1u);
        lastflag = (old == TAIL_BLOCKS - 1);
    }
    __syncthreads();
    if (!lastflag) return;

    // ---- final combine (last block only) ----
    __threadfence();
    double c13[13];
    if (tid < TAIL_BLOCKS) {
        const double* p = bs + (size_t)tid * 16;
        #pragma unroll
        for (int k = 0; k < 13; ++k) c13[k] = p[k];
    } else {
        #pragma unroll
        for (int k = 0; k < 13; ++k) c13[k] = 0.0;
    }
    for (int o = 32; o; o >>= 1) {
        #pragma unroll
        for (int k = 0; k < 13; ++k) c13[k] += __shfl_down(c13[k], o);
    }
    if (lane == 0) {
        #pragma unroll
        for (int k = 0; k < 13; ++k) lred[wave][k] = c13[k];
    }
    __syncthreads();
    if (tid == 0) {
        double S[13];
        #pragma unroll
        for (int k = 0; k < 13; ++k)
            S[k] = lred[0][k] + lred[1][k] + lred[2][k] + lred[3][k];
        double m_d1f = S[0] / (double)(B_ * NF);
        double m_d2f = S[1] / (double)(B_ * MT);
        double m_d1c = S[2] / (double)(B_ * NC);
        double m_d2c = S[3] / (double)(B_ * MT);
        double loss_align_fine   = 0.5 * (m_d1f + m_d2f);
        double loss_align_coarse = 0.5 * (m_d1c + m_d2c);
        double loss_ref = S[4] / (double)(B_ * NF);
        double loss_rot = 0.0, loss_geo = 0.0;
        for (int b = 0; b < B_; ++b) {
            double dn = sqrt(S[5 + b]) - sqrt(S[7 + b]);
            loss_rot += dn * dn;
            double dv = (S[9 + b] - S[11 + b]) / 6.0;
            loss_geo += dv * dv;
        }
        loss_rot /= (double)B_;
        loss_geo /= (double)B_;
        out[0] = (float)(loss_rot + loss_ref + loss_align_coarse + loss_align_fine + loss_geo);
    }
}

extern "C" void kernel_launch(void* const* d_in, const int* in_sizes, int n_in,
                              void* d_out, int out_size, void* d_ws, size_t ws_size,
                              hipStream_t stream)
{
    const float* src_coarse = (const float*)d_in[0];
    const float* src_fine   = (const float*)d_in[1];
    const float* tgt        = (const float*)d_in[2];
    float* out = (float*)d_out;
    char*  ws  = (char*)d_ws;

    // ws layout (bytes), everything written before read — no init needed:
    //   [0,        2097152)  u64 pfr[16][16384]   fine-rows (d,j) partials
    //   [2097152,  3145728)  u32 pfc[16][16384]   fine-cols value partials
    //   [3145728,  3276800)  u32 pcr[32][1024]    coarse-rows value partials
    //   [3276800,  3407872)  u32 pcc[2][16384]    coarse-cols value partials
    //   [3407872,  3432960)  double bs[196][16]   per-tail-block sums
    //   [3432960,  3432964)  u32 counter          (zeroed by pairmin_all blk 0)
    u64*      pfr     = (u64*)(ws);
    unsigned* pfc     = (unsigned*)(ws + 2097152);
    unsigned* pcr     = (unsigned*)(ws + 3145728);
    unsigned* pcc     = (unsigned*)(ws + 3276800);
    double*   bs      = (double*)(ws + 3407872);
    unsigned* counter = (unsigned*)(ws + 3432960);

    pairmin_all<<<dim3(1152), TPB, 0, stream>>>(
        src_coarse, src_fine, tgt, pfr, pfc, pcr, pcc, counter);
    tail_all<<<dim3(TAIL_BLOCKS), TPB, 0, stream>>>(
        src_fine, tgt, pfr, pfc, pcr, pcc, bs, counter, out);
}

// Round 2
// 117.538 us; speedup vs baseline: 1.1019x; 1.0801x over previous
//
#include <hip/hip_runtime.h>
#include <stdint.h>
#include <float.h>

using u64 = unsigned long long;
typedef float v2f __attribute__((ext_vector_type(2)));

constexpr int B_ = 2;
constexpr int NC = 512;
constexpr int NF = 8192;
constexpr int MT = 8192;

constexpr int TPB  = 256;
constexpr int RPB  = 512;          // rows per block for 2-row (coarse) passes
constexpr int TILE = 256;
constexpr int CF   = 16;           // fine chunks (j-split) -> 512 j per chunk
constexpr int TAIL_BLOCKS = 196;   // 64 fine-rows + 64 fine-cols + 4 coarse-rows + 64 coarse-cols

#define DEVINL __device__ __forceinline__

// ---------------------------------------------------------------------------
// pairmin: each block computes, for its rows of P, the min over its j-chunk of
//   d = max((xx+qq) - 2*xy, 0)
// computed bit-exactly vs numpy fp32:
//   2*xy is computed as ((2x0)q0 + (2x1)q1) + (2x2)q2  — power-of-2 scaling
//   commutes with round-to-nearest, so this equals 2*((x0q0+x1q1)+x2q2) exactly.
// The max(.,0) clamp is applied ONCE at pack time (monotone => bit-exact value).
//
// R2 = row-pairs per thread. Fine passes use R2=2 (4 rows/thread) so each
// 16B ds_read_b128 of a q-point feeds 4 distance evals — this halves LDS-unit
// traffic, which R1 counters showed to be the binding pipe (~43.5 us floor at
// 2 rows/thread). Prefetch depth 4 (qa/qb ping-pong) keeps VGPR ~85: no spill
// (R1's depth-8 spilled: WRITE_SIZE 3.3MB -> 10.6MB at VGPR_Count=64).
// Results go to per-chunk partial slots: NO atomics, NO sentinel init.
// ---------------------------------------------------------------------------
template<bool ARGMIN, int R2>
DEVINL void pairmin_body(const float* __restrict__ P, const float* __restrict__ Q,
                         int nP, int nQ, int b, int row_base, int j0, int ntiles,
                         int chunk, int nRowsTot,
                         u64* __restrict__ outPack, unsigned* __restrict__ outVal,
                         float4* tile)
{
#pragma clang fp contract(off)
    const int tid = threadIdx.x;
    v2f tx0[R2], tx1[R2], tx2[R2], txx[R2], dbest[R2];
    int jb[2 * R2];
    #pragma unroll
    for (int r = 0; r < R2; ++r) {
        const int row0 = row_base + tid + (2 * r) * TPB;
        const int row1 = row_base + tid + (2 * r + 1) * TPB;
        const float* p0 = P + ((size_t)b * nP + row0) * 3;
        const float* p1 = P + ((size_t)b * nP + row1) * 3;
        float a0 = p0[0], a1 = p0[1], a2 = p0[2];
        float e0 = p1[0], e1 = p1[1], e2 = p1[2];
        tx0[r] = v2f{2.0f * a0, 2.0f * e0};
        tx1[r] = v2f{2.0f * a1, 2.0f * e1};
        tx2[r] = v2f{2.0f * a2, 2.0f * e2};
        txx[r] = v2f{(a0*a0 + a1*a1) + a2*a2, (e0*e0 + e1*e1) + e2*e2};
        dbest[r] = v2f{FLT_MAX, FLT_MAX};
        jb[2 * r] = 0; jb[2 * r + 1] = 0;
    }

    // distance eval: 5 pk (dot, contract off) + pk_add + pk_sub + pk_min per pair
    auto PROC = [&](const float4 qv, const int j) {
#pragma clang fp contract(off)
        #pragma unroll
        for (int r = 0; r < R2; ++r) {
            v2f s = (tx0[r] * qv.x + tx1[r] * qv.y) + tx2[r] * qv.z;  // == 2*xy
            v2f d = (txx[r] + qv.w) - s;                               // (xx+qq)-2xy
            if (ARGMIN) {
                bool c0 = d.x < dbest[r].x;                 // strict: first idx wins
                bool c1 = d.y < dbest[r].y;
                dbest[r] = __builtin_elementwise_min(d, dbest[r]);
                jb[2 * r]     = c0 ? j : jb[2 * r];
                jb[2 * r + 1] = c1 ? j : jb[2 * r + 1];
            } else {
                dbest[r] = __builtin_elementwise_min(dbest[r], d);
            }
        }
    };

    {
        // stage-ahead registers for next tile (hides global latency under compute)
        const float* q = Q + ((size_t)b * nQ + j0 + tid) * 3;
        float nq0 = q[0], nq1 = q[1], nq2 = q[2];

        for (int t = 0; t < ntiles; ++t) {
            __syncthreads();
            tile[tid] = make_float4(nq0, nq1, nq2, (nq0*nq0 + nq1*nq1) + nq2*nq2);
            if (t + 1 < ntiles) {
                const float* qn = Q + ((size_t)b * nQ + j0 + (t + 1) * TILE + tid) * 3;
                nq0 = qn[0]; nq1 = qn[1]; nq2 = qn[2];
            }
            __syncthreads();
            const int jbase = j0 + t * TILE;

            float4 qa[4], qb[4];
            #pragma unroll
            for (int u = 0; u < 4; ++u) qa[u] = tile[u];

            for (int jj = 0; jj < TILE; jj += 8) {
                #pragma unroll
                for (int u = 0; u < 4; ++u) qb[u] = tile[jj + 4 + u];
                #pragma unroll
                for (int u = 0; u < 4; ++u) PROC(qa[u], jbase + jj + u);
                #pragma unroll
                for (int u = 0; u < 4; ++u) qa[u] = tile[(jj + 8 + u) & (TILE - 1)];
                #pragma unroll
                for (int u = 0; u < 4; ++u) PROC(qb[u], jbase + jj + 4 + u);
            }
        }
    }

    const v2f vzero = {0.0f, 0.0f};
    const size_t o0 = (size_t)chunk * nRowsTot + (size_t)b * nP;
    #pragma unroll
    for (int r = 0; r < R2; ++r) {
        v2f dcl = __builtin_elementwise_max(dbest[r], vzero);   // clamp once, exact
        const int row0 = row_base + tid + (2 * r) * TPB;
        const int row1 = row_base + tid + (2 * r + 1) * TPB;
        if (ARGMIN) {
            outPack[o0 + row0] = ((u64)__float_as_uint(dcl.x) << 32) | (unsigned)jb[2 * r];
            outPack[o0 + row1] = ((u64)__float_as_uint(dcl.y) << 32) | (unsigned)jb[2 * r + 1];
        } else {
            outVal[o0 + row0] = __float_as_uint(dcl.x);
            outVal[o0 + row1] = __float_as_uint(dcl.y);
        }
    }
}

// All four pairwise passes, one dispatch, 640 blocks (fine first for balance).
//  [0,  256)  fine-rows  : P=fine(8192), Q=tgt, ARGMIN, 4 rows/thr, 16ch x 8yb x 2b
//  [256,512)  fine-cols  : P=tgt(8192),  Q=fine,        4 rows/thr, 16ch x 8yb x 2b
//  [512,576)  coarse-rows: P=coarse(512),Q=tgt,         2 rows/thr, 32ch x 2b
//  [576,640)  coarse-cols: P=tgt(8192),  Q=coarse,      2 rows/thr, 2ch x 16yb x 2b
// Partial layouts (pfr/pfc/pcr/pcc) are IDENTICAL to the previous kernel:
// tail_all is unchanged.
__global__ __launch_bounds__(TPB, 4) void pairmin_all(
    const float* __restrict__ coarse, const float* __restrict__ fine,
    const float* __restrict__ tgt,
    u64* __restrict__ pfr, unsigned* __restrict__ pfc,
    unsigned* __restrict__ pcr, unsigned* __restrict__ pcc,
    unsigned* __restrict__ counter)
{
    __shared__ float4 tile[TILE];
    const int bx = blockIdx.x;
    if (bx == 0 && threadIdx.x == 0) *counter = 0;   // init for tail_all
    if (bx < 256) {
        int chunk = bx & 15, yb = (bx >> 4) & 7, b = bx >> 7;
        pairmin_body<true, 2>(fine, tgt, NF, MT, b, yb * 1024, chunk * (MT / CF), 2,
                              chunk, B_ * NF, pfr, nullptr, tile);
    } else if (bx < 512) {
        int i = bx - 256;
        int chunk = i & 15, yb = (i >> 4) & 7, b = i >> 7;
        pairmin_body<false, 2>(tgt, fine, MT, NF, b, yb * 1024, chunk * (NF / CF), 2,
                               chunk, B_ * MT, nullptr, pfc, tile);
    } else if (bx < 576) {
        int i = bx - 512;
        int chunk = i & 31, b = i >> 5;
        pairmin_body<false, 1>(coarse, tgt, NC, MT, b, 0, chunk * TILE, 1,
                               chunk, B_ * NC, nullptr, pcr, tile);
    } else {
        int i = bx - 576;
        int chunk = i & 1, yb = (i >> 1) & 15, b = i >> 5;
        pairmin_body<false, 1>(tgt, coarse, MT, NC, b, yb * RPB, chunk * TILE, 1,
                               chunk, B_ * MT, nullptr, pcc, tile);
    }
}

// ---------------------------------------------------------------------------
// tail_all: everything after the pairwise passes, one dispatch. (unchanged)
//  [0,  64) fine-rows: reduce 16 partials (u64 min = min d then min j), gather,
//           chamfer d1 sum, loss_ref/rot stats, wedge volumes (LDS halo).
//  [64,128) fine-cols value reduce -> d2f
//  [128,132) coarse-rows -> d1c
//  [132,196) coarse-cols -> d2c
// Each block writes its partial sums to bs[bx][16]; last-arriving block (via
// device-scope counter) reduces bs and writes the final scalar.
// ---------------------------------------------------------------------------
__global__ __launch_bounds__(TPB) void tail_all(
    const float* __restrict__ fine, const float* __restrict__ tgt,
    const u64* __restrict__ pfr, const unsigned* __restrict__ pfc,
    const unsigned* __restrict__ pcr, const unsigned* __restrict__ pcc,
    double* __restrict__ bs, unsigned* __restrict__ counter,
    float* __restrict__ out)
{
    __shared__ float sp[TPB + 2][3], yp[TPB + 2][3];
    __shared__ double redw[4][9];
    __shared__ double lred[4][13];
    __shared__ int lastflag;
    const int bx = blockIdx.x, tid = threadIdx.x;
    const int wave = tid >> 6, lane = tid & 63;

    double v_s = 0, v_d2f = 0, v_d1c = 0, v_d2c = 0, v_yd2 = 0, v_zs = 0, v_zt = 0;
    double vs = 0, vt = 0;
    int role_b = 0;

    if (bx < 64) {                              // ---- fine-rows ----
        const int base = bx * TPB;
        const int g = base + tid;
        const int b = base >> 13;  role_b = b;
        u64 best = pfr[g];
        #pragma unroll
        for (int c = 1; c < CF; ++c) {
            u64 p = pfr[(size_t)c * (B_ * NF) + g];
            best = p < best ? p : best;
        }
        float d1 = __uint_as_float((unsigned)(best >> 32));
        int idx  = (int)(best & 0xffffffffULL);
        float s = sqrtf(fmaxf(d1, 1e-12f));
        const float* y  = tgt  + ((size_t)b * MT + idx) * 3;
        const float* sr = fine + (size_t)g * 3;
        float y0 = y[0],  y1 = y[1],  y2 = y[2];
        float s0 = sr[0], s1 = sr[1], s2 = sr[2];
        yp[tid][0] = y0; yp[tid][1] = y1; yp[tid][2] = y2;
        sp[tid][0] = s0; sp[tid][1] = s1; sp[tid][2] = s2;
        const int base_b = base & (NF - 1);
        if (tid < 2 && base_b + TPB + tid < NF) {        // halo rows
            int g2 = base + TPB + tid;
            u64 b2 = pfr[g2];
            #pragma unroll
            for (int c = 1; c < CF; ++c) {
                u64 p = pfr[(size_t)c * (B_ * NF) + g2];
                b2 = p < b2 ? p : b2;
            }
            int i2 = (int)(b2 & 0xffffffffULL);
            const float* yh = tgt  + ((size_t)b * MT + i2) * 3;
            const float* sh = fine + (size_t)g2 * 3;
            #pragma unroll
            for (int k = 0; k < 3; ++k) { yp[TPB + tid][k] = yh[k]; sp[TPB + tid][k] = sh[k]; }
        }
        __syncthreads();
        v_s = s;
        float yd = s1 - y1;
        v_yd2 = (double)(yd * yd);
        v_zs  = (double)(s2 * s2);
        v_zt  = (double)(y2 * y2);
        int rb = base_b + tid;
        if (rb <= NF - 3) {          // same f32 exprs as the verified R3 kernel
            {
                const float* a = sp[tid]; const float* c = sp[tid+1]; const float* e = sp[tid+2];
                float c0 = a[1]*c[2] - a[2]*c[1];
                float c1 = a[2]*c[0] - a[0]*c[2];
                float c2 = a[0]*c[1] - a[1]*c[0];
                vs = (double)(c0*e[0] + c1*e[1] + c2*e[2]);
            }
            {
                const float* a = yp[tid]; const float* c = yp[tid+1]; const float* e = yp[tid+2];
                float c0 = a[1]*c[2] - a[2]*c[1];
                float c1 = a[2]*c[0] - a[0]*c[2];
                float c2 = a[0]*c[1] - a[1]*c[0];
                vt = (double)(c0*e[0] + c1*e[1] + c2*e[2]);
            }
        }
    } else if (bx < 128) {                      // ---- fine-cols ----
        const int g = (bx - 64) * TPB + tid;
        unsigned best = pfc[g];
        #pragma unroll
        for (int c = 1; c < CF; ++c) best = min(best, pfc[(size_t)c * (B_ * MT) + g]);
        v_d2f = (double)sqrtf(fmaxf(__uint_as_float(best), 1e-12f));
    } else if (bx < 132) {                      // ---- coarse-rows ----
        const int g = (bx - 128) * TPB + tid;
        unsigned best = pcr[g];
        #pragma unroll
        for (int c = 1; c < 32; ++c) best = min(best, pcr[(size_t)c * (B_ * NC) + g]);
        v_d1c = (double)sqrtf(fmaxf(__uint_as_float(best), 1e-12f));
    } else {                                    // ---- coarse-cols ----
        const int g = (bx - 132) * TPB + tid;
        unsigned best = min(pcc[g], pcc[(size_t)(B_ * MT) + g]);
        v_d2c = (double)sqrtf(fmaxf(__uint_as_float(best), 1e-12f));
    }

    // block reduce 9 values
    double r9[9] = {v_s, v_d2f, v_d1c, v_d2c, v_yd2, v_zs, v_zt, vs, vt};
    for (int o = 32; o; o >>= 1) {
        #pragma unroll
        for (int k = 0; k < 9; ++k) r9[k] += __shfl_down(r9[k], o);
    }
    if (lane == 0) {
        #pragma unroll
        for (int k = 0; k < 9; ++k) redw[wave][k] = r9[k];
    }
    __syncthreads();
    if (tid == 0) {
        double t9[9];
        #pragma unroll
        for (int k = 0; k < 9; ++k)
            t9[k] = redw[0][k] + redw[1][k] + redw[2][k] + redw[3][k];
        double* o = bs + (size_t)bx * 16;
        #pragma unroll
        for (int k = 0; k < 16; ++k) o[k] = 0.0;
        o[0] = t9[0]; o[1] = t9[1]; o[2] = t9[2]; o[3] = t9[3]; o[4] = t9[4];
        o[5 + role_b]  = t9[5];   // zs
        o[7 + role_b]  = t9[6];   // zt
        o[9 + role_b]  = t9[7];   // vs
        o[11 + role_b] = t9[8];   // vt
        __threadfence();
        unsigned old = atomicAdd(counter, 1u);
        lastflag = (old == TAIL_BLOCKS - 1);
    }
    __syncthreads();
    if (!lastflag) return;

    // ---- final combine (last block only) ----
    __threadfence();
    double c13[13];
    if (tid < TAIL_BLOCKS) {
        const double* p = bs + (size_t)tid * 16;
        #pragma unroll
        for (int k = 0; k < 13; ++k) c13[k] = p[k];
    } else {
        #pragma unroll
        for (int k = 0; k < 13; ++k) c13[k] = 0.0;
    }
    for (int o = 32; o; o >>= 1) {
        #pragma unroll
        for (int k = 0; k < 13; ++k) c13[k] += __shfl_down(c13[k], o);
    }
    if (lane == 0) {
        #pragma unroll
        for (int k = 0; k < 13; ++k) lred[wave][k] = c13[k];
    }
    __syncthreads();
    if (tid == 0) {
        double S[13];
        #pragma unroll
        for (int k = 0; k < 13; ++k)
            S[k] = lred[0][k] + lred[1][k] + lred[2][k] + lred[3][k];
        double m_d1f = S[0] / (double)(B_ * NF);
        double m_d2f = S[1] / (double)(B_ * MT);
        double m_d1c = S[2] / (double)(B_ * NC);
        double m_d2c = S[3] / (double)(B_ * MT);
        double loss_align_fine   = 0.5 * (m_d1f + m_d2f);
        double loss_align_coarse = 0.5 * (m_d1c + m_d2c);
        double loss_ref = S[4] / (double)(B_ * NF);
        double loss_rot = 0.0, loss_geo = 0.0;
        for (int b = 0; b < B_; ++b) {
            double dn = sqrt(S[5 + b]) - sqrt(S[7 + b]);
            loss_rot += dn * dn;
            double dv = (S[9 + b] - S[11 + b]) / 6.0;
            loss_geo += dv * dv;
        }
        loss_rot /= (double)B_;
        loss_geo /= (double)B_;
        out[0] = (float)(loss_rot + loss_ref + loss_align_coarse + loss_align_fine + loss_geo);
    }
}

extern "C" void kernel_launch(void* const* d_in, const int* in_sizes, int n_in,
                              void* d_out, int out_size, void* d_ws, size_t ws_size,
                              hipStream_t stream)
{
    const float* src_coarse = (const float*)d_in[0];
    const float* src_fine   = (const float*)d_in[1];
    const float* tgt        = (const float*)d_in[2];
    float* out = (float*)d_out;
    char*  ws  = (char*)d_ws;

    // ws layout (bytes), everything written before read — no init needed:
    //   [0,        2097152)  u64 pfr[16][16384]   fine-rows (d,j) partials
    //   [2097152,  3145728)  u32 pfc[16][16384]   fine-cols value partials
    //   [3145728,  3276800)  u32 pcr[32][1024]    coarse-rows value partials
    //   [3276800,  3407872)  u32 pcc[2][16384]    coarse-cols value partials
    //   [3407872,  3432960)  double bs[196][16]   per-tail-block sums
    //   [3432960,  3432964)  u32 counter          (zeroed by pairmin_all blk 0)
    u64*      pfr     = (u64*)(ws);
    unsigned* pfc     = (unsigned*)(ws + 2097152);
    unsigned* pcr     = (unsigned*)(ws + 3145728);
    unsigned* pcc     = (unsigned*)(ws + 3276800);
    double*   bs      = (double*)(ws + 3407872);
    unsigned* counter = (unsigned*)(ws + 3432960);

    pairmin_all<<<dim3(640), TPB, 0, stream>>>(
        src_coarse, src_fine, tgt, pfr, pfc, pcr, pcc, counter);
    tail_all<<<dim3(TAIL_BLOCKS), TPB, 0, stream>>>(
        src_fine, tgt, pfr, pfc, pcr, pcc, bs, counter, out);
}